// Round 10
// baseline (277.244 us; speedup 1.0000x reference)
//
#include <hip/hip_runtime.h>
#include <stdint.h>

#define MTOK   4096   // B*S
#define DMODEL 1024
#define SEQ    2048
#define NH     16
#define HD     64
#define LDP    68     // epilogue merge row stride (floats): (4q+d)%32 balanced
#define QSCL   0.18033688f   // 0.125 * log2(e): softmax in exp2 domain
#define NWORDS (2 * SEQ * SEQ / 64)   // 64-entry mask bit-words

typedef _Float16 h8  __attribute__((ext_vector_type(8)));
typedef _Float16 h4  __attribute__((ext_vector_type(4)));
typedef _Float16 h2  __attribute__((ext_vector_type(2)));
typedef __fp16   fp16x2 __attribute__((ext_vector_type(2)));
typedef float    f16v __attribute__((ext_vector_type(16)));
typedef float    f4  __attribute__((ext_vector_type(4)));
typedef int      iv4 __attribute__((ext_vector_type(4)));

typedef __attribute__((address_space(1))) const unsigned int g_u32;
typedef __attribute__((address_space(3))) unsigned int       l_u32;

// global->LDS direct DMA, 16 B/lane; LDS dest = wave-uniform base + lane*16.
__device__ __forceinline__ void g2l16(const void* g, void* l) {
    __builtin_amdgcn_global_load_lds((g_u32*)(unsigned long long)g,
                                     (l_u32*)(unsigned int)(unsigned long long)l,
                                     16, 0, 0);
}

__device__ __forceinline__ h2 pkrtz(float a, float b) {
    fp16x2 r = __builtin_amdgcn_cvt_pkrtz(a, b);
    return __builtin_bit_cast(h2, r);
}

#if __has_builtin(__builtin_amdgcn_exp2f)
#define E2(x) __builtin_amdgcn_exp2f(x)
#else
#define E2(x) exp2f(x)
#endif

// acc += sum of the two fp16 halves of dword v (v_dot2_f32_f16 with ones)
__device__ __forceinline__ float dot2sum(int v, float acc) {
    h2 a = __builtin_bit_cast(h2, v);
#if __has_builtin(__builtin_amdgcn_fdot2)
    h2 one2 = {(_Float16)1.0f, (_Float16)1.0f};
    return __builtin_amdgcn_fdot2(a, one2, acc, false);
#else
    return acc + (float)a.x + (float)a.y;
#endif
}

// ------ prep (R10: W-only + mask; x-conversion fused into qkv staging) ------
// z=0..3: Wq/Wk/Wv/Wo fp32->fp16 (amortized: W reused 32x in qkv).
// z=4: mask bitmask. Grid (512, 5); W = 2 iters/thread, mask = 1.
__global__ __launch_bounds__(256) void prep_kernel(
    const float* __restrict__ s0, const float* __restrict__ s1,
    const float* __restrict__ s2, const float* __restrict__ s3,
    _Float16* __restrict__ d0, _Float16* __restrict__ d1,
    _Float16* __restrict__ d2, _Float16* __restrict__ d3,
    const unsigned char* __restrict__ mb, const unsigned int* __restrict__ mu,
    unsigned long long* __restrict__ mout) {
    const int z = blockIdx.y;
    const int gid = blockIdx.x * 256 + threadIdx.x;
    const int stride = gridDim.x * 256;
    if (z < 4) {
        const float* s = (z == 0) ? s0 : (z == 1) ? s1 : (z == 2) ? s2 : s3;
        _Float16* d = (z == 0) ? d0 : (z == 1) ? d1 : (z == 2) ? d2 : d3;
        const int n4 = DMODEL * DMODEL / 4;
        for (int i = gid; i < n4; i += stride) {
            float4 v = ((const float4*)s)[i];
            h4 o = {(_Float16)v.x, (_Float16)v.y, (_Float16)v.z, (_Float16)v.w};
            ((h4*)d)[i] = o;
        }
    } else {
        // local byteflag: scan first 8192 mask bytes (L2-cached, all blocks)
        __shared__ int wsum[4];
        int cnt = 0;
        const uchar4* mp4 = (const uchar4*)mb;
#pragma unroll
        for (int i = 0; i < 8; ++i) {
            uchar4 v = mp4[threadIdx.x * 8 + i];
            cnt += (v.x != 0) + (v.y != 0) + (v.z != 0) + (v.w != 0);
        }
#pragma unroll
        for (int off = 32; off > 0; off >>= 1) cnt += __shfl_down(cnt, off, 64);
        if ((threadIdx.x & 63) == 0) wsum[threadIdx.x >> 6] = cnt;
        __syncthreads();
        const int byteflag = (wsum[0] + wsum[1] + wsum[2] + wsum[3]) > 2500;

        for (int w = gid; w < NWORDS; w += stride) {
            unsigned long long bits = 0ull;
            if (byteflag) {
                const uint4* p = (const uint4*)(mb + (size_t)w * 64);
#pragma unroll
                for (int i = 0; i < 4; ++i) {
                    uint4 v = p[i];
                    unsigned dw[4] = {v.x, v.y, v.z, v.w};
#pragma unroll
                    for (int j = 0; j < 4; ++j) {
                        unsigned d = dw[j];
                        unsigned nib = (unsigned)((d & 0xFFu) != 0)
                                     | ((unsigned)((d & 0xFF00u) != 0) << 1)
                                     | ((unsigned)((d & 0xFF0000u) != 0) << 2)
                                     | ((unsigned)((d >> 24) != 0) << 3);
                        bits |= (unsigned long long)nib << (i * 16 + j * 4);
                    }
                }
            } else {
                const uint4* p = (const uint4*)(mu + (size_t)w * 64);
#pragma unroll
                for (int i = 0; i < 16; ++i) {
                    uint4 v = p[i];
                    unsigned nib = (unsigned)(v.x != 0u)
                                 | ((unsigned)(v.y != 0u) << 1)
                                 | ((unsigned)(v.z != 0u) << 2)
                                 | ((unsigned)(v.w != 0u) << 3);
                    bits |= (unsigned long long)nib << (i * 4);
                }
            }
            mout[w] = bits;
        }
    }
}

// ------------- fp16 MFMA GEMM: out = A @ W^T + bias, BK=64, swizzled -------
// MODE 0: fp32 out[m][n].  MODE 1: fp16 head layout, value*scale (Q).
// MODE 3: K pre-swizzled attn-tile layout [bh][s/64][d/8][s%64][d%8].
// MODE 4: V^T (operand swap) pre-swizzled [bh][k/64][(k%64)/8][d][k%8].
// AF32 (R10): A staged as fp32 via g2l16 (32KB tile, own XOR swizzle
// pos = c ^ ((r&7)<<1), parity-preserving), converted fp32->fp16 with RTN
// v_cvt at frag read (bit-identical to the old prep conversion). Removes
// the prep x-conversion round-trip (~72 MB traffic + a kernel pass).
// LDS passed in (R9 lesson: per-instantiation static __shared__ unions).
template <int MODE, int BM, int BN, bool AF32>
__device__ __forceinline__ void gemm16_body(void* __restrict__ AsbV,
                                            _Float16* __restrict__ Bsb,
                                            const void* __restrict__ Av,
                                            const _Float16* __restrict__ W,
                                            const float* __restrict__ bias,
                                            void* __restrict__ outv,
                                            float scale, int m0, int n0) {
    constexpr int NI = BM / 32, NJ = BN / 32;
    constexpr int WM = BM / 2,  WN = BN / 2;
    constexpr int RA = AF32 ? (BM / 16) : (BM / 32);  // g2l16 rounds for A
    constexpr int RB = BN / 32;
    const int tid = threadIdx.x;
    const int wv = tid >> 6, lane = tid & 63;
    const int l15 = lane & 15, g = lane >> 4;
    const int wy = wv >> 1, wx = wv & 1;

    f4 acc[NI][NJ];
#pragma unroll
    for (int i = 0; i < NI; ++i)
#pragma unroll
        for (int j = 0; j < NJ; ++j) acc[i][j] = (f4){0.f, 0.f, 0.f, 0.f};

    const char* Ab = (const char*)Av;
    const char* Wb = (const char*)W;
    int srowA[RA], scolA[RA];
#pragma unroll
    for (int r = 0; r < RA; ++r) {
        const int o = (r * 256 + tid) * 16;
        if (AF32) {
            srowA[r] = o >> 8;                                  // 256 B/row
            scolA[r] = (((o >> 4) & 15) ^ ((srowA[r] & 7) << 1)) * 16;
        } else {
            srowA[r] = o >> 7;                                  // 128 B/row
            scolA[r] = (((o >> 4) & 7) ^ (srowA[r] & 7)) * 16;
        }
    }
    int srowB[RB], scolB[RB];
#pragma unroll
    for (int r = 0; r < RB; ++r) {
        const int o = (r * 256 + tid) * 16;
        srowB[r] = o >> 7;
        scolB[r] = (((o >> 4) & 7) ^ (srowB[r] & 7)) * 16;
    }

    for (int kt = 0; kt < 16; ++kt) {
        const int k0a = kt * (AF32 ? 256 : 128);  // A bytes along K
        const int k0w = kt * 128;                 // W bytes along K
        __syncthreads();           // prior ds_reads done
#pragma unroll
        for (int r = 0; r < RA; ++r)
            g2l16(Ab + (size_t)(m0 + srowA[r]) * (AF32 ? 4096 : 2048)
                      + k0a + scolA[r],
                  (char*)AsbV + (r * 256 + tid) * 16);
#pragma unroll
        for (int r = 0; r < RB; ++r)
            g2l16(Wb + (size_t)(n0 + srowB[r]) * 2048 + k0w + scolB[r],
                  (char*)Bsb + (r * 256 + tid) * 16);
        __syncthreads();           // drains vmcnt (compiler-inserted)

#pragma unroll
        for (int ksub = 0; ksub < 2; ++ksub) {
            h8 af[NI], bf[NJ];
#pragma unroll
            for (int t = 0; t < NI; ++t) {
                const int row = wy * WM + t * 16 + l15;
                if (AF32) {
                    const float* rp = (const float*)AsbV + row * 64;
                    const int p0 = (2 * (ksub * 4 + g)) ^ ((row & 7) << 1);
                    f4 lo = *(const f4*)(rp + p0 * 4);
                    f4 hi = *(const f4*)(rp + (p0 ^ 1) * 4);
                    h8 v;
                    v[0] = (_Float16)lo[0]; v[1] = (_Float16)lo[1];
                    v[2] = (_Float16)lo[2]; v[3] = (_Float16)lo[3];
                    v[4] = (_Float16)hi[0]; v[5] = (_Float16)hi[1];
                    v[6] = (_Float16)hi[2]; v[7] = (_Float16)hi[3];
                    af[t] = v;
                } else {
                    const _Float16* As = (const _Float16*)AsbV;
                    const int pos = (ksub * 4 + g) ^ (row & 7);
                    af[t] = *(const h8*)(As + row * 64 + pos * 8);
                }
            }
#pragma unroll
            for (int t = 0; t < NJ; ++t) {
                const int row = wx * WN + t * 16 + l15;
                const int pos = (ksub * 4 + g) ^ (row & 7);
                bf[t] = *(const h8*)(Bsb + row * 64 + pos * 8);
            }
#pragma unroll
            for (int i = 0; i < NI; ++i)
#pragma unroll
                for (int j = 0; j < NJ; ++j) {
                    if (MODE == 4)  // swapped: D rows = n (W), cols = m (X)
                        acc[i][j] = __builtin_amdgcn_mfma_f32_16x16x32_f16(
                            bf[j], af[i], acc[i][j], 0, 0, 0);
                    else
                        acc[i][j] = __builtin_amdgcn_mfma_f32_16x16x32_f16(
                            af[i], bf[j], acc[i][j], 0, 0, 0);
                }
        }
    }

    // epilogue: C/D layout col=lane&15, row=g*4+reg
#pragma unroll
    for (int j = 0; j < NJ; ++j) {
#pragma unroll
        for (int i = 0; i < NI; ++i) {
            if (MODE == 4) {
                // m = k (token), r iterates n -> (h,d). V_sw tile image.
                const int m = m0 + wy * WM + i * 16 + l15;
                const int b = m >> 11, s = m & 2047;
                const int koff = (s >> 6) * 4096 + ((s >> 3) & 7) * 512 + (s & 7);
#pragma unroll
                for (int r = 0; r < 4; ++r) {
                    const int n = n0 + wx * WN + j * 16 + g * 4 + r;
                    const int h = n >> 6, d = n & 63;
                    ((_Float16*)outv)[(size_t)(b * NH + h) * 131072 + koff + d * 8] =
                        (_Float16)(acc[i][j][r] + bias[n]);
                }
            } else {
                const int n = n0 + wx * WN + j * 16 + l15;
                const float bb = bias[n];
                const int mbase = m0 + wy * WM + i * 16 + g * 4;
                if (MODE == 1) {
                    const int h = n >> 6, d = n & 63;
#pragma unroll
                    for (int r = 0; r < 4; ++r) {
                        const int m = mbase + r;
                        const int b = m >> 11, s = m & 2047;
                        ((_Float16*)outv)[(((size_t)(b * NH + h)) * SEQ + s) * HD + d] =
                            (_Float16)((acc[i][j][r] + bb) * scale);
                    }
                } else if (MODE == 3) {
                    // n -> (h,d) fixed; r iterates m -> s. K_sw tile image.
                    const int h = n >> 6, d = n & 63;
                    const int doff = (d >> 3) * 512 + (d & 7);
#pragma unroll
                    for (int r = 0; r < 4; ++r) {
                        const int m = mbase + r;
                        const int b = m >> 11, s = m & 2047;
                        ((_Float16*)outv)[(size_t)(b * NH + h) * 131072 +
                                          (s >> 6) * 4096 + doff + (s & 63) * 8] =
                            (_Float16)(acc[i][j][r] + bb);
                    }
                } else {
#pragma unroll
                    for (int r = 0; r < 4; ++r)
                        ((float*)outv)[(size_t)(mbase + r) * DMODEL + n] =
                            acc[i][j][r] + bb;
                }
            }
        }
    }
}

// qkv (R10): A = raw fp32 inputs (AF32 staging); XCD swizzle — each XCD owns
// one W n-panel (256 KB, L2-resident). LDS 48 KB -> 3 blocks/CU (= grid cap).
__global__ __launch_bounds__(256) void qkv_gemm16_kernel(
    const float* __restrict__ xq, const float* __restrict__ xk,
    const float* __restrict__ xv,
    const _Float16* __restrict__ Wq, const _Float16* __restrict__ Wk,
    const _Float16* __restrict__ Wv,
    const float* __restrict__ bq, const float* __restrict__ bk,
    const float* __restrict__ bv,
    _Float16* __restrict__ q_out, _Float16* __restrict__ k_out,
    _Float16* __restrict__ vt_out) {
    __shared__ __align__(16) float    AsbF[128 * 64];   // 32 KB, shared arms
    __shared__ __align__(16) _Float16 Bsb[128 * 64];    // 16 KB
    const int lin = blockIdx.x + 32 * blockIdx.y;       // 0..255
    const int swz = (lin & 7) * 32 + (lin >> 3);        // bijective
    const int m0 = (swz & 31) * 128, n0 = (swz >> 5) * 128;
    const int z = blockIdx.z;
    if (z == 0)
        gemm16_body<1, 128, 128, true>(AsbF, Bsb, xq, Wq, bq, (void*)q_out,
                                       QSCL, m0, n0);
    else if (z == 1)
        gemm16_body<3, 128, 128, true>(AsbF, Bsb, xk, Wk, bk, (void*)k_out,
                                       1.0f, m0, n0);
    else
        gemm16_body<4, 128, 128, true>(AsbF, Bsb, xv, Wv, bv, (void*)vt_out,
                                       1.0f, m0, n0);
}

__global__ __launch_bounds__(256) void out_gemm16_kernel(
    const _Float16* __restrict__ X, const _Float16* __restrict__ W,
    const float* __restrict__ bias, float* __restrict__ out) {
    __shared__ __align__(16) _Float16 Asb[64 * 64];
    __shared__ __align__(16) _Float16 Bsb[128 * 64];
    const int lin = blockIdx.x + 64 * blockIdx.y;       // 0..511
    const int swz = (lin & 7) * 64 + (lin >> 3);        // bijective
    const int m0 = (swz & 63) * 64, n0 = (swz >> 6) * 128;
    gemm16_body<0, 64, 128, false>(Asb, Bsb, X, W, bias, (void*)out,
                                   1.0f, m0, n0);
}

// ---- MFMA flash attention (unchanged from R9): pre-swizzled K/V + XCD swz ----
// 512 threads, waves 0-3 = group 0 (even 64-k tiles), 4-7 = group 1 (odd);
// per-group double-buffered K/V; one barrier/iter; nothing lives across the
// barrier; LUT mask (R4); interleaved sc0/sc1 QK (R4).
//  - K/V PRE-SWIZZLED into the LDS tile image [tile][c][r] by the qkv GEMM
//    epilogue -> g2l16 is identity: coalesced source (R4's property) AND
//    conflict-free [c][r] frag reads (R6: SQ_LDS_BANK_CONFLICT == 0).
//  - XCD-aware block swizzle: 4 whole bh per XCD -> K/V L2-local.
__global__ __launch_bounds__(512, 4) void attn_kernel(
    const _Float16* __restrict__ Q, const _Float16* __restrict__ Ksw,
    const _Float16* __restrict__ Vsw,
    const unsigned long long* __restrict__ mbits,
    _Float16* __restrict__ out) {
    // halves: K tiles [grp][buf] @ grp*8192+buf*4096 | V @ 16384+idem | LUT @ 32768
    __shared__ __align__(16) _Float16 shm[32768 + 64];

    const int tid = threadIdx.x;
    const int wv = tid >> 6, lane = tid & 63;
    const int grp = wv >> 2, wvg = wv & 3;
    const int l31 = lane & 31, hi = lane >> 5;
    // XCD swizzle: hw dispatch round-robins linear id across 8 XCDs; remap
    // so each XCD gets 4 whole bh (64 blocks = 4 bh x 16 q-tiles).
    const int lin = blockIdx.x + 16 * blockIdx.y;       // 0..511
    const int swz = (lin & 7) * 64 + (lin >> 3);        // bijective
    const int bh = swz >> 4;
    const int q0 = (swz & 15) * 128;
    const int b = bh >> 4, h = bh & 15;
    const size_t bho = (size_t)bh * (SEQ * HD);
    const int qrow = q0 + wvg * 32 + l31;  // this lane's q

    // mask-nibble -> fp16 AND-mask LUT (bit set = disallowed = zero)
    if (tid < 16) {
        unsigned mlo = (tid & 1 ? 0u : 0xFFFFu) | (tid & 2 ? 0u : 0xFFFF0000u);
        unsigned mhi = (tid & 4 ? 0u : 0xFFFFu) | (tid & 8 ? 0u : 0xFFFF0000u);
        ((uint2*)&shm[32768])[tid] = (uint2){mlo, mhi};
    }

    // Q B-frags, register-resident (pre-scaled by 0.125*log2e)
    h8 qf[4];
    const _Float16* qp = Q + bho + (size_t)qrow * HD;
#pragma unroll
    for (int ks = 0; ks < 4; ++ks) qf[ks] = *(const h8*)(qp + ks * 16 + hi * 8);

    f16v Ot[2];
#pragma unroll
    for (int mt = 0; mt < 2; ++mt)
#pragma unroll
        for (int r = 0; r < 16; ++r) Ot[mt][r] = 0.f;
    float l_r = 0.f;

    // staging: identity DMA. Tile t (8KB) lives at Ksw + bho + t*4096 halves
    // in the exact LDS image; 2 rounds of 256 threads x 16B cover it.
    const int gtid = tid & 255;
    const _Float16* ksrc = Ksw + bho + grp * 4096 + gtid * 8;
    const _Float16* vsrc = Vsw + bho + grp * 4096 + gtid * 8;
    const unsigned long long* mrow =
        mbits + ((size_t)b * SEQ + qrow) * (SEQ / 64);

    _Float16* KTb = &shm[grp * 8192];
    _Float16* VTb = &shm[16384 + grp * 8192];

#define STAGE(buf) do {                                                     \
    char* kd = (char*)(KTb + (buf) * 4096);                                 \
    char* vd = (char*)(VTb + (buf) * 4096);                                 \
    g2l16(ksrc,        kd + gtid * 16);                                     \
    g2l16(ksrc + 2048, kd + 4096 + gtid * 16);                              \
    g2l16(vsrc,        vd + gtid * 16);                                     \
    g2l16(vsrc + 2048, vd + 4096 + gtid * 16);                              \
    ksrc += 8192; vsrc += 8192;                                             \
} while (0)

    uint2 mw = *(const uint2*)(mrow + grp);  // mask of this group's tile 0
    STAGE(0);
    __syncthreads();   // drains vmcnt; LUT also visible

    const uint2* lut = (const uint2*)&shm[32768];
    int rp[8][2];

    for (int it = 0; it < 16; ++it) {
        const int cur = it & 1;
        const int kt = 2 * it + grp;
        uint2 mwn;
        if (it < 15) {  // prefetch group's next tile into other buffer
            STAGE(cur ^ 1);
            mwn = *(const uint2*)(mrow + kt + 2);
        }
        const _Float16* Kc = KTb + cur * 4096;
        const _Float16* Vc = VTb + cur * 4096;

        // ---- S^T = K . Q^T : lane pair holds 64 scores of its q ----
        f16v sc0, sc1;
#pragma unroll
        for (int r = 0; r < 16; ++r) { sc0[r] = 0.f; sc1[r] = 0.f; }
        __builtin_amdgcn_s_setprio(1);
#pragma unroll
        for (int ks = 0; ks < 4; ++ks) {
            const int po = (2 * ks + hi) * 512;   // chunk column, halves
            h8 kf0 = *(const h8*)(Kc + po + l31 * 8);
            h8 kf1 = *(const h8*)(Kc + po + 256 + l31 * 8);
            sc0 = __builtin_amdgcn_mfma_f32_32x32x16_f16(kf0, qf[ks], sc0, 0, 0, 0);
            sc1 = __builtin_amdgcn_mfma_f32_32x32x16_f16(kf1, qf[ks], sc1, 0, 0, 0);
        }
        __builtin_amdgcn_s_setprio(0);

        // ---- softmax: exp2 unconditionally, AND with LUT mask, pack ----
#pragma unroll
        for (int mt = 0; mt < 2; ++mt) {
            const unsigned w = mt ? mw.y : mw.x;
            const unsigned wl = w >> (hi * 4);
            const f16v& s = mt ? sc1 : sc0;
#pragma unroll
            for (int g4 = 0; g4 < 4; ++g4) {
                const uint2 m2 = lut[(wl >> (g4 * 8)) & 15u];
                float p0 = E2(s[g4 * 4 + 0]);
                float p1 = E2(s[g4 * 4 + 1]);
                float p2 = E2(s[g4 * 4 + 2]);
                float p3 = E2(s[g4 * 4 + 3]);
                rp[mt * 4 + g4][0] =
                    __builtin_bit_cast(int, pkrtz(p0, p1)) & (int)m2.x;
                rp[mt * 4 + g4][1] =
                    __builtin_bit_cast(int, pkrtz(p2, p3)) & (int)m2.y;
            }
        }

        // ---- permlane exchange -> PV B-frags; l via dot2; O^T += V^T.P ----
        float l0 = 0.f, l1 = 0.f;
#pragma unroll
        for (int ks = 0; ks < 4; ++ks) {
            int a0 = rp[2 * ks][0], a1 = rp[2 * ks][1];
            int b0 = rp[2 * ks + 1][0], b1 = rp[2 * ks + 1][1];
            asm volatile("v_permlane32_swap_b32 %0, %1" : "+v"(a0), "+v"(b0));
            asm volatile("v_permlane32_swap_b32 %0, %1" : "+v"(a1), "+v"(b1));
            l0 = dot2sum(a0, l0); l1 = dot2sum(a1, l1);
            l0 = dot2sum(b0, l0); l1 = dot2sum(b1, l1);
            iv4 pi = {a0, a1, b0, b1};
            h8 pf = __builtin_bit_cast(h8, pi);
            const int po = (2 * ks + hi) * 512;
            h8 vf0 = *(const h8*)(Vc + po + l31 * 8);
            h8 vf1 = *(const h8*)(Vc + po + 256 + l31 * 8);
            __builtin_amdgcn_s_setprio(1);
            Ot[0] = __builtin_amdgcn_mfma_f32_32x32x16_f16(vf0, pf, Ot[0], 0, 0, 0);
            Ot[1] = __builtin_amdgcn_mfma_f32_32x32x16_f16(vf1, pf, Ot[1], 0, 0, 0);
            __builtin_amdgcn_s_setprio(0);
        }
        l_r += l0 + l1;

        if (it < 15) mw = mwn;
        __syncthreads();  // one barrier/iter; drains prefetch g2l16s
    }
#undef STAGE

    // ---- epilogue: merge groups via LDS (stride LDP=68), store fp16 ----
    l_r += __shfl_xor(l_r, 32);                 // merge hi halves within group
    float* mrg = (float*)&shm[0];               // 128 x LDP floats
    float* lm  = mrg + 128 * LDP;               // 128 floats
    const int ql = wvg * 32 + l31;
    if (grp == 1) {
#pragma unroll
        for (int mt = 0; mt < 2; ++mt)
#pragma unroll
            for (int t = 0; t < 4; ++t) {
                f4 v = {Ot[mt][t * 4 + 0], Ot[mt][t * 4 + 1],
                        Ot[mt][t * 4 + 2], Ot[mt][t * 4 + 3]};
                *(f4*)&mrg[ql * LDP + mt * 32 + t * 8 + hi * 4] = v;
            }
        if (hi == 0) lm[ql] = l_r;
    }
    __syncthreads();
    if (grp == 0) {
        l_r += lm[ql];
        const float inv = 1.0f / l_r;
        _Float16* op = out + ((size_t)b * SEQ + qrow) * DMODEL + h * HD;
#pragma unroll
        for (int mt = 0; mt < 2; ++mt)
#pragma unroll
            for (int t = 0; t < 4; ++t) {
                const int d = mt * 32 + t * 8 + hi * 4;
                f4 v = *(const f4*)&mrg[ql * LDP + d];
                h4 ov = {(_Float16)((Ot[mt][t * 4 + 0] + v.x) * inv),
                         (_Float16)((Ot[mt][t * 4 + 1] + v.y) * inv),
                         (_Float16)((Ot[mt][t * 4 + 2] + v.z) * inv),
                         (_Float16)((Ot[mt][t * 4 + 3] + v.w) * inv)};
                *(h4*)(op + d) = ov;
            }
    }
}

extern "C" void kernel_launch(void* const* d_in, const int* in_sizes, int n_in,
                              void* d_out, int out_size, void* d_ws, size_t ws_size,
                              hipStream_t stream) {
    const float* query = (const float*)d_in[0];
    const float* key_  = (const float*)d_in[1];
    const float* value = (const float*)d_in[2];
    const void*  mask  = d_in[3];
    const float* Wq = (const float*)d_in[4];
    const float* Wk = (const float*)d_in[5];
    const float* Wv = (const float*)d_in[6];
    const float* Wo = (const float*)d_in[7];
    const float* bq = (const float*)d_in[8];
    const float* bk = (const float*)d_in[9];
    const float* bv = (const float*)d_in[10];
    const float* bo = (const float*)d_in[11];

    // ws (R10): xq/xk/xv staging buffers eliminated (qkv reads fp32 inputs
    // directly via AF32 staging). ~41 MB total.
    char* ws = (char*)d_ws;
    _Float16* Wqh = (_Float16*)(ws + 256);
    _Float16* Wkh = Wqh + (size_t)DMODEL * DMODEL;
    _Float16* Wvh = Wkh + (size_t)DMODEL * DMODEL;
    _Float16* Woh = Wvh + (size_t)DMODEL * DMODEL;
    _Float16* q_ws  = Woh + (size_t)DMODEL * DMODEL;
    _Float16* k_ws  = q_ws + (size_t)MTOK * DMODEL;
    _Float16* vt_ws = k_ws + (size_t)MTOK * DMODEL;
    _Float16* a_ws  = vt_ws + (size_t)MTOK * DMODEL;
    unsigned long long* mb_ws =
        (unsigned long long*)(a_ws + (size_t)MTOK * DMODEL);  // 1 MB

    prep_kernel<<<dim3(512, 5), 256, 0, stream>>>(
        Wq, Wk, Wv, Wo, Wqh, Wkh, Wvh, Woh,
        (const unsigned char*)mask, (const unsigned int*)mask, mb_ws);

    dim3 gqkv(MTOK / 128, DMODEL / 128, 3);
    qkv_gemm16_kernel<<<gqkv, 256, 0, stream>>>(query, key_, value,
                                                Wqh, Wkh, Wvh,
                                                bq, bk, bv, q_ws, k_ws, vt_ws);

    dim3 gattn(SEQ / 128, 2 * NH);
    attn_kernel<<<gattn, 512, 0, stream>>>(q_ws, k_ws, vt_ws, mb_ws, a_ws);

    dim3 gout(MTOK / 64, DMODEL / 128);
    out_gemm16_kernel<<<gout, 256, 0, stream>>>(a_ws, Woh, bo, (float*)d_out);
}

// Round 11
// 270.145 us; speedup vs baseline: 1.0263x; 1.0263x over previous
//
#include <hip/hip_runtime.h>
#include <stdint.h>

#define MTOK   4096   // B*S
#define DMODEL 1024
#define SEQ    2048
#define NH     16
#define HD     64
#define LDP    68     // epilogue merge row stride (floats): (4q+d)%32 balanced
#define QSCL   0.18033688f   // 0.125 * log2(e): softmax in exp2 domain
#define NWORDS (2 * SEQ * SEQ / 64)   // 64-entry mask bit-words

typedef _Float16 h8  __attribute__((ext_vector_type(8)));
typedef _Float16 h4  __attribute__((ext_vector_type(4)));
typedef _Float16 h2  __attribute__((ext_vector_type(2)));
typedef __fp16   fp16x2 __attribute__((ext_vector_type(2)));
typedef float    f16v __attribute__((ext_vector_type(16)));
typedef float    f4  __attribute__((ext_vector_type(4)));
typedef int      iv4 __attribute__((ext_vector_type(4)));

typedef __attribute__((address_space(1))) const unsigned int g_u32;
typedef __attribute__((address_space(3))) unsigned int       l_u32;

// global->LDS direct DMA, 16 B/lane; LDS dest = wave-uniform base + lane*16.
__device__ __forceinline__ void g2l16(const void* g, void* l) {
    __builtin_amdgcn_global_load_lds((g_u32*)(unsigned long long)g,
                                     (l_u32*)(unsigned int)(unsigned long long)l,
                                     16, 0, 0);
}

__device__ __forceinline__ h2 pkrtz(float a, float b) {
    fp16x2 r = __builtin_amdgcn_cvt_pkrtz(a, b);
    return __builtin_bit_cast(h2, r);
}

#if __has_builtin(__builtin_amdgcn_exp2f)
#define E2(x) __builtin_amdgcn_exp2f(x)
#else
#define E2(x) exp2f(x)
#endif

// acc += sum of the two fp16 halves of dword v (v_dot2_f32_f16 with ones)
__device__ __forceinline__ float dot2sum(int v, float acc) {
    h2 a = __builtin_bit_cast(h2, v);
#if __has_builtin(__builtin_amdgcn_fdot2)
    h2 one2 = {(_Float16)1.0f, (_Float16)1.0f};
    return __builtin_amdgcn_fdot2(a, one2, acc, false);
#else
    return acc + (float)a.x + (float)a.y;
#endif
}

// ------ prep (W-only + mask; x-conversion fused into qkv staging) ------
__global__ __launch_bounds__(256) void prep_kernel(
    const float* __restrict__ s0, const float* __restrict__ s1,
    const float* __restrict__ s2, const float* __restrict__ s3,
    _Float16* __restrict__ d0, _Float16* __restrict__ d1,
    _Float16* __restrict__ d2, _Float16* __restrict__ d3,
    const unsigned char* __restrict__ mb, const unsigned int* __restrict__ mu,
    unsigned long long* __restrict__ mout) {
    const int z = blockIdx.y;
    const int gid = blockIdx.x * 256 + threadIdx.x;
    const int stride = gridDim.x * 256;
    if (z < 4) {
        const float* s = (z == 0) ? s0 : (z == 1) ? s1 : (z == 2) ? s2 : s3;
        _Float16* d = (z == 0) ? d0 : (z == 1) ? d1 : (z == 2) ? d2 : d3;
        const int n4 = DMODEL * DMODEL / 4;
        for (int i = gid; i < n4; i += stride) {
            float4 v = ((const float4*)s)[i];
            h4 o = {(_Float16)v.x, (_Float16)v.y, (_Float16)v.z, (_Float16)v.w};
            ((h4*)d)[i] = o;
        }
    } else {
        // local byteflag: scan first 8192 mask bytes (L2-cached, all blocks)
        __shared__ int wsum[4];
        int cnt = 0;
        const uchar4* mp4 = (const uchar4*)mb;
#pragma unroll
        for (int i = 0; i < 8; ++i) {
            uchar4 v = mp4[threadIdx.x * 8 + i];
            cnt += (v.x != 0) + (v.y != 0) + (v.z != 0) + (v.w != 0);
        }
#pragma unroll
        for (int off = 32; off > 0; off >>= 1) cnt += __shfl_down(cnt, off, 64);
        if ((threadIdx.x & 63) == 0) wsum[threadIdx.x >> 6] = cnt;
        __syncthreads();
        const int byteflag = (wsum[0] + wsum[1] + wsum[2] + wsum[3]) > 2500;

        for (int w = gid; w < NWORDS; w += stride) {
            unsigned long long bits = 0ull;
            if (byteflag) {
                const uint4* p = (const uint4*)(mb + (size_t)w * 64);
#pragma unroll
                for (int i = 0; i < 4; ++i) {
                    uint4 v = p[i];
                    unsigned dw[4] = {v.x, v.y, v.z, v.w};
#pragma unroll
                    for (int j = 0; j < 4; ++j) {
                        unsigned d = dw[j];
                        unsigned nib = (unsigned)((d & 0xFFu) != 0)
                                     | ((unsigned)((d & 0xFF00u) != 0) << 1)
                                     | ((unsigned)((d & 0xFF0000u) != 0) << 2)
                                     | ((unsigned)((d >> 24) != 0) << 3);
                        bits |= (unsigned long long)nib << (i * 16 + j * 4);
                    }
                }
            } else {
                const uint4* p = (const uint4*)(mu + (size_t)w * 64);
#pragma unroll
                for (int i = 0; i < 16; ++i) {
                    uint4 v = p[i];
                    unsigned nib = (unsigned)(v.x != 0u)
                                 | ((unsigned)(v.y != 0u) << 1)
                                 | ((unsigned)(v.z != 0u) << 2)
                                 | ((unsigned)(v.w != 0u) << 3);
                    bits |= (unsigned long long)nib << (i * 4);
                }
            }
            mout[w] = bits;
        }
    }
}

// ------------- fp16 MFMA GEMM: out = A @ W^T + bias, BK=64, swizzled -------
// MODE 0: fp32 out[m][n].  MODE 1: fp16 head layout, value*scale (Q).
// MODE 3: K pre-swizzled attn-tile layout [bh][s/64][d/8][s%64][d%8].
// MODE 4: V^T (operand swap) pre-swizzled [bh][k/64][(k%64)/8][d][k%8].
// AF32: A staged as fp32 via g2l16; R11: 4-bit XOR swizzle s = row&15
// (R10's (row&7)<<1 spread reads over only 8 even positions -> 4-way
// conflicts, measured 3.1M). fp32->fp16 RTN cvt at frag read (bit-identical
// to old prep conversion). LDS passed in (R9 lesson).
template <int MODE, int BM, int BN, bool AF32>
__device__ __forceinline__ void gemm16_body(void* __restrict__ AsbV,
                                            _Float16* __restrict__ Bsb,
                                            const void* __restrict__ Av,
                                            const _Float16* __restrict__ W,
                                            const float* __restrict__ bias,
                                            void* __restrict__ outv,
                                            float scale, int m0, int n0) {
    constexpr int NI = BM / 32, NJ = BN / 32;
    constexpr int WM = BM / 2,  WN = BN / 2;
    constexpr int RA = AF32 ? (BM / 16) : (BM / 32);  // g2l16 rounds for A
    constexpr int RB = BN / 32;
    const int tid = threadIdx.x;
    const int wv = tid >> 6, lane = tid & 63;
    const int l15 = lane & 15, g = lane >> 4;
    const int wy = wv >> 1, wx = wv & 1;

    f4 acc[NI][NJ];
#pragma unroll
    for (int i = 0; i < NI; ++i)
#pragma unroll
        for (int j = 0; j < NJ; ++j) acc[i][j] = (f4){0.f, 0.f, 0.f, 0.f};

    const char* Ab = (const char*)Av;
    const char* Wb = (const char*)W;
    int srowA[RA], scolA[RA];
#pragma unroll
    for (int r = 0; r < RA; ++r) {
        const int o = (r * 256 + tid) * 16;
        if (AF32) {
            srowA[r] = o >> 8;                                  // 256 B/row
            scolA[r] = (((o >> 4) & 15) ^ (srowA[r] & 15)) * 16;
        } else {
            srowA[r] = o >> 7;                                  // 128 B/row
            scolA[r] = (((o >> 4) & 7) ^ (srowA[r] & 7)) * 16;
        }
    }
    int srowB[RB], scolB[RB];
#pragma unroll
    for (int r = 0; r < RB; ++r) {
        const int o = (r * 256 + tid) * 16;
        srowB[r] = o >> 7;
        scolB[r] = (((o >> 4) & 7) ^ (srowB[r] & 7)) * 16;
    }

    for (int kt = 0; kt < 16; ++kt) {
        const int k0a = kt * (AF32 ? 256 : 128);  // A bytes along K
        const int k0w = kt * 128;                 // W bytes along K
        __syncthreads();           // prior ds_reads done
#pragma unroll
        for (int r = 0; r < RA; ++r)
            g2l16(Ab + (size_t)(m0 + srowA[r]) * (AF32 ? 4096 : 2048)
                      + k0a + scolA[r],
                  (char*)AsbV + (r * 256 + tid) * 16);
#pragma unroll
        for (int r = 0; r < RB; ++r)
            g2l16(Wb + (size_t)(n0 + srowB[r]) * 2048 + k0w + scolB[r],
                  (char*)Bsb + (r * 256 + tid) * 16);
        __syncthreads();           // drains vmcnt (compiler-inserted)

#pragma unroll
        for (int ksub = 0; ksub < 2; ++ksub) {
            h8 af[NI], bf[NJ];
#pragma unroll
            for (int t = 0; t < NI; ++t) {
                const int row = wy * WM + t * 16 + l15;
                if (AF32) {
                    const float* rp = (const float*)AsbV + row * 64;
                    const int p0 = (2 * (ksub * 4 + g)) ^ (row & 15);
                    f4 lo = *(const f4*)(rp + p0 * 4);
                    f4 hi = *(const f4*)(rp + (p0 ^ 1) * 4);
                    h8 v;
                    v[0] = (_Float16)lo[0]; v[1] = (_Float16)lo[1];
                    v[2] = (_Float16)lo[2]; v[3] = (_Float16)lo[3];
                    v[4] = (_Float16)hi[0]; v[5] = (_Float16)hi[1];
                    v[6] = (_Float16)hi[2]; v[7] = (_Float16)hi[3];
                    af[t] = v;
                } else {
                    const _Float16* As = (const _Float16*)AsbV;
                    const int pos = (ksub * 4 + g) ^ (row & 7);
                    af[t] = *(const h8*)(As + row * 64 + pos * 8);
                }
            }
#pragma unroll
            for (int t = 0; t < NJ; ++t) {
                const int row = wx * WN + t * 16 + l15;
                const int pos = (ksub * 4 + g) ^ (row & 7);
                bf[t] = *(const h8*)(Bsb + row * 64 + pos * 8);
            }
#pragma unroll
            for (int i = 0; i < NI; ++i)
#pragma unroll
                for (int j = 0; j < NJ; ++j) {
                    if (MODE == 4)  // swapped: D rows = n (W), cols = m (X)
                        acc[i][j] = __builtin_amdgcn_mfma_f32_16x16x32_f16(
                            bf[j], af[i], acc[i][j], 0, 0, 0);
                    else
                        acc[i][j] = __builtin_amdgcn_mfma_f32_16x16x32_f16(
                            af[i], bf[j], acc[i][j], 0, 0, 0);
                }
        }
    }

    // epilogue: C/D layout col=lane&15, row=g*4+reg
#pragma unroll
    for (int j = 0; j < NJ; ++j) {
#pragma unroll
        for (int i = 0; i < NI; ++i) {
            if (MODE == 4) {
                // m = k (token), r iterates n -> (h,d). V_sw tile image.
                const int m = m0 + wy * WM + i * 16 + l15;
                const int b = m >> 11, s = m & 2047;
                const int koff = (s >> 6) * 4096 + ((s >> 3) & 7) * 512 + (s & 7);
#pragma unroll
                for (int r = 0; r < 4; ++r) {
                    const int n = n0 + wx * WN + j * 16 + g * 4 + r;
                    const int h = n >> 6, d = n & 63;
                    ((_Float16*)outv)[(size_t)(b * NH + h) * 131072 + koff + d * 8] =
                        (_Float16)(acc[i][j][r] + bias[n]);
                }
            } else {
                const int n = n0 + wx * WN + j * 16 + l15;
                const float bb = bias[n];
                const int mbase = m0 + wy * WM + i * 16 + g * 4;
                if (MODE == 1) {
                    const int h = n >> 6, d = n & 63;
#pragma unroll
                    for (int r = 0; r < 4; ++r) {
                        const int m = mbase + r;
                        const int b = m >> 11, s = m & 2047;
                        ((_Float16*)outv)[(((size_t)(b * NH + h)) * SEQ + s) * HD + d] =
                            (_Float16)((acc[i][j][r] + bb) * scale);
                    }
                } else if (MODE == 3) {
                    // n -> (h,d) fixed; r iterates m -> s. K_sw tile image.
                    const int h = n >> 6, d = n & 63;
                    const int doff = (d >> 3) * 512 + (d & 7);
#pragma unroll
                    for (int r = 0; r < 4; ++r) {
                        const int m = mbase + r;
                        const int b = m >> 11, s = m & 2047;
                        ((_Float16*)outv)[(size_t)(b * NH + h) * 131072 +
                                          (s >> 6) * 4096 + doff + (s & 63) * 8] =
                            (_Float16)(acc[i][j][r] + bb);
                    }
                } else {
#pragma unroll
                    for (int r = 0; r < 4; ++r)
                        ((float*)outv)[(size_t)(mbase + r) * DMODEL + n] =
                            acc[i][j][r] + bb;
                }
            }
        }
    }
}

// qkv (R11): XCD owns a contiguous M-CHUNK, n iterates fastest.
// R10's inverted mapping (n-panel per XCD) destroyed A reuse: every XCD
// streamed the whole 16MB fp32 A (FETCH 200MB, qkv 80us). Now per XCD:
// A chunk = 4 m-panels = 2MB fp32 + full W 2MB fp16 -> fits 4MB L2;
// A HBM-fetched once (FETCH ~55MB predicted).
__global__ __launch_bounds__(256) void qkv_gemm16_kernel(
    const float* __restrict__ xq, const float* __restrict__ xk,
    const float* __restrict__ xv,
    const _Float16* __restrict__ Wq, const _Float16* __restrict__ Wk,
    const _Float16* __restrict__ Wv,
    const float* __restrict__ bq, const float* __restrict__ bk,
    const float* __restrict__ bv,
    _Float16* __restrict__ q_out, _Float16* __restrict__ k_out,
    _Float16* __restrict__ vt_out) {
    __shared__ __align__(16) float    AsbF[128 * 64];   // 32 KB, shared arms
    __shared__ __align__(16) _Float16 Bsb[128 * 64];    // 16 KB
    const int lin = blockIdx.x + 32 * blockIdx.y;       // 0..255
    const int x = lin & 7, j = lin >> 3;                // XCD, seq in XCD
    const int m0 = (x * 4 + (j >> 3)) * 128;            // 4 m-panels per XCD
    const int n0 = (j & 7) * 128;                       // n fastest
    const int z = blockIdx.z;
    if (z == 0)
        gemm16_body<1, 128, 128, true>(AsbF, Bsb, xq, Wq, bq, (void*)q_out,
                                       QSCL, m0, n0);
    else if (z == 1)
        gemm16_body<3, 128, 128, true>(AsbF, Bsb, xk, Wk, bk, (void*)k_out,
                                       1.0f, m0, n0);
    else
        gemm16_body<4, 128, 128, true>(AsbF, Bsb, xv, Wv, bv, (void*)vt_out,
                                       1.0f, m0, n0);
}

__global__ __launch_bounds__(256) void out_gemm16_kernel(
    const _Float16* __restrict__ X, const _Float16* __restrict__ W,
    const float* __restrict__ bias, float* __restrict__ out) {
    __shared__ __align__(16) _Float16 Asb[64 * 64];
    __shared__ __align__(16) _Float16 Bsb[128 * 64];
    const int lin = blockIdx.x + 64 * blockIdx.y;       // 0..511
    const int x = lin & 7, j = lin >> 3;                // XCD, seq in XCD
    const int m0 = (x * 8 + (j >> 3)) * 64;             // 8 m-panels per XCD
    const int n0 = (j & 7) * 128;                       // n fastest
    gemm16_body<0, 64, 128, false>(Asb, Bsb, X, W, bias, (void*)out,
                                   1.0f, m0, n0);
}

// ---- MFMA flash attention (unchanged): pre-swizzled K/V + XCD swz ----
__global__ __launch_bounds__(512, 4) void attn_kernel(
    const _Float16* __restrict__ Q, const _Float16* __restrict__ Ksw,
    const _Float16* __restrict__ Vsw,
    const unsigned long long* __restrict__ mbits,
    _Float16* __restrict__ out) {
    // halves: K tiles [grp][buf] @ grp*8192+buf*4096 | V @ 16384+idem | LUT @ 32768
    __shared__ __align__(16) _Float16 shm[32768 + 64];

    const int tid = threadIdx.x;
    const int wv = tid >> 6, lane = tid & 63;
    const int grp = wv >> 2, wvg = wv & 3;
    const int l31 = lane & 31, hi = lane >> 5;
    // XCD swizzle: each XCD gets 4 whole bh (64 blocks = 4 bh x 16 q-tiles).
    const int lin = blockIdx.x + 16 * blockIdx.y;       // 0..511
    const int swz = (lin & 7) * 64 + (lin >> 3);        // bijective
    const int bh = swz >> 4;
    const int q0 = (swz & 15) * 128;
    const int b = bh >> 4, h = bh & 15;
    const size_t bho = (size_t)bh * (SEQ * HD);
    const int qrow = q0 + wvg * 32 + l31;  // this lane's q

    // mask-nibble -> fp16 AND-mask LUT (bit set = disallowed = zero)
    if (tid < 16) {
        unsigned mlo = (tid & 1 ? 0u : 0xFFFFu) | (tid & 2 ? 0u : 0xFFFF0000u);
        unsigned mhi = (tid & 4 ? 0u : 0xFFFFu) | (tid & 8 ? 0u : 0xFFFF0000u);
        ((uint2*)&shm[32768])[tid] = (uint2){mlo, mhi};
    }

    // Q B-frags, register-resident (pre-scaled by 0.125*log2e)
    h8 qf[4];
    const _Float16* qp = Q + bho + (size_t)qrow * HD;
#pragma unroll
    for (int ks = 0; ks < 4; ++ks) qf[ks] = *(const h8*)(qp + ks * 16 + hi * 8);

    f16v Ot[2];
#pragma unroll
    for (int mt = 0; mt < 2; ++mt)
#pragma unroll
        for (int r = 0; r < 16; ++r) Ot[mt][r] = 0.f;
    float l_r = 0.f;

    // staging: identity DMA. Tile t (8KB) lives at Ksw + bho + t*4096 halves
    // in the exact LDS image; 2 rounds of 256 threads x 16B cover it.
    const int gtid = tid & 255;
    const _Float16* ksrc = Ksw + bho + grp * 4096 + gtid * 8;
    const _Float16* vsrc = Vsw + bho + grp * 4096 + gtid * 8;
    const unsigned long long* mrow =
        mbits + ((size_t)b * SEQ + qrow) * (SEQ / 64);

    _Float16* KTb = &shm[grp * 8192];
    _Float16* VTb = &shm[16384 + grp * 8192];

#define STAGE(buf) do {                                                     \
    char* kd = (char*)(KTb + (buf) * 4096);                                 \
    char* vd = (char*)(VTb + (buf) * 4096);                                 \
    g2l16(ksrc,        kd + gtid * 16);                                     \
    g2l16(ksrc + 2048, kd + 4096 + gtid * 16);                              \
    g2l16(vsrc,        vd + gtid * 16);                                     \
    g2l16(vsrc + 2048, vd + 4096 + gtid * 16);                              \
    ksrc += 8192; vsrc += 8192;                                             \
} while (0)

    uint2 mw = *(const uint2*)(mrow + grp);  // mask of this group's tile 0
    STAGE(0);
    __syncthreads();   // drains vmcnt; LUT also visible

    const uint2* lut = (const uint2*)&shm[32768];
    int rp[8][2];

    for (int it = 0; it < 16; ++it) {
        const int cur = it & 1;
        const int kt = 2 * it + grp;
        uint2 mwn;
        if (it < 15) {  // prefetch group's next tile into other buffer
            STAGE(cur ^ 1);
            mwn = *(const uint2*)(mrow + kt + 2);
        }
        const _Float16* Kc = KTb + cur * 4096;
        const _Float16* Vc = VTb + cur * 4096;

        // ---- S^T = K . Q^T : lane pair holds 64 scores of its q ----
        f16v sc0, sc1;
#pragma unroll
        for (int r = 0; r < 16; ++r) { sc0[r] = 0.f; sc1[r] = 0.f; }
        __builtin_amdgcn_s_setprio(1);
#pragma unroll
        for (int ks = 0; ks < 4; ++ks) {
            const int po = (2 * ks + hi) * 512;   // chunk column, halves
            h8 kf0 = *(const h8*)(Kc + po + l31 * 8);
            h8 kf1 = *(const h8*)(Kc + po + 256 + l31 * 8);
            sc0 = __builtin_amdgcn_mfma_f32_32x32x16_f16(kf0, qf[ks], sc0, 0, 0, 0);
            sc1 = __builtin_amdgcn_mfma_f32_32x32x16_f16(kf1, qf[ks], sc1, 0, 0, 0);
        }
        __builtin_amdgcn_s_setprio(0);

        // ---- softmax: exp2 unconditionally, AND with LUT mask, pack ----
#pragma unroll
        for (int mt = 0; mt < 2; ++mt) {
            const unsigned w = mt ? mw.y : mw.x;
            const unsigned wl = w >> (hi * 4);
            const f16v& s = mt ? sc1 : sc0;
#pragma unroll
            for (int g4 = 0; g4 < 4; ++g4) {
                const uint2 m2 = lut[(wl >> (g4 * 8)) & 15u];
                float p0 = E2(s[g4 * 4 + 0]);
                float p1 = E2(s[g4 * 4 + 1]);
                float p2 = E2(s[g4 * 4 + 2]);
                float p3 = E2(s[g4 * 4 + 3]);
                rp[mt * 4 + g4][0] =
                    __builtin_bit_cast(int, pkrtz(p0, p1)) & (int)m2.x;
                rp[mt * 4 + g4][1] =
                    __builtin_bit_cast(int, pkrtz(p2, p3)) & (int)m2.y;
            }
        }

        // ---- permlane exchange -> PV B-frags; l via dot2; O^T += V^T.P ----
        float l0 = 0.f, l1 = 0.f;
#pragma unroll
        for (int ks = 0; ks < 4; ++ks) {
            int a0 = rp[2 * ks][0], a1 = rp[2 * ks][1];
            int b0 = rp[2 * ks + 1][0], b1 = rp[2 * ks + 1][1];
            asm volatile("v_permlane32_swap_b32 %0, %1" : "+v"(a0), "+v"(b0));
            asm volatile("v_permlane32_swap_b32 %0, %1" : "+v"(a1), "+v"(b1));
            l0 = dot2sum(a0, l0); l1 = dot2sum(a1, l1);
            l0 = dot2sum(b0, l0); l1 = dot2sum(b1, l1);
            iv4 pi = {a0, a1, b0, b1};
            h8 pf = __builtin_bit_cast(h8, pi);
            const int po = (2 * ks + hi) * 512;
            h8 vf0 = *(const h8*)(Vc + po + l31 * 8);
            h8 vf1 = *(const h8*)(Vc + po + 256 + l31 * 8);
            __builtin_amdgcn_s_setprio(1);
            Ot[0] = __builtin_amdgcn_mfma_f32_32x32x16_f16(vf0, pf, Ot[0], 0, 0, 0);
            Ot[1] = __builtin_amdgcn_mfma_f32_32x32x16_f16(vf1, pf, Ot[1], 0, 0, 0);
            __builtin_amdgcn_s_setprio(0);
        }
        l_r += l0 + l1;

        if (it < 15) mw = mwn;
        __syncthreads();  // one barrier/iter; drains prefetch g2l16s
    }
#undef STAGE

    // ---- epilogue: merge groups via LDS (stride LDP=68), store fp16 ----
    l_r += __shfl_xor(l_r, 32);                 // merge hi halves within group
    float* mrg = (float*)&shm[0];               // 128 x LDP floats
    float* lm  = mrg + 128 * LDP;               // 128 floats
    const int ql = wvg * 32 + l31;
    if (grp == 1) {
#pragma unroll
        for (int mt = 0; mt < 2; ++mt)
#pragma unroll
            for (int t = 0; t < 4; ++t) {
                f4 v = {Ot[mt][t * 4 + 0], Ot[mt][t * 4 + 1],
                        Ot[mt][t * 4 + 2], Ot[mt][t * 4 + 3]};
                *(f4*)&mrg[ql * LDP + mt * 32 + t * 8 + hi * 4] = v;
            }
        if (hi == 0) lm[ql] = l_r;
    }
    __syncthreads();
    if (grp == 0) {
        l_r += lm[ql];
        const float inv = 1.0f / l_r;
        _Float16* op = out + ((size_t)b * SEQ + qrow) * DMODEL + h * HD;
#pragma unroll
        for (int mt = 0; mt < 2; ++mt)
#pragma unroll
            for (int t = 0; t < 4; ++t) {
                const int d = mt * 32 + t * 8 + hi * 4;
                f4 v = *(const f4*)&mrg[ql * LDP + d];
                h4 ov = {(_Float16)((Ot[mt][t * 4 + 0] + v.x) * inv),
                         (_Float16)((Ot[mt][t * 4 + 1] + v.y) * inv),
                         (_Float16)((Ot[mt][t * 4 + 2] + v.z) * inv),
                         (_Float16)((Ot[mt][t * 4 + 3] + v.w) * inv)};
                *(h4*)(op + d) = ov;
            }
    }
}

extern "C" void kernel_launch(void* const* d_in, const int* in_sizes, int n_in,
                              void* d_out, int out_size, void* d_ws, size_t ws_size,
                              hipStream_t stream) {
    const float* query = (const float*)d_in[0];
    const float* key_  = (const float*)d_in[1];
    const float* value = (const float*)d_in[2];
    const void*  mask  = d_in[3];
    const float* Wq = (const float*)d_in[4];
    const float* Wk = (const float*)d_in[5];
    const float* Wv = (const float*)d_in[6];
    const float* Wo = (const float*)d_in[7];
    const float* bq = (const float*)d_in[8];
    const float* bk = (const float*)d_in[9];
    const float* bv = (const float*)d_in[10];
    const float* bo = (const float*)d_in[11];

    char* ws = (char*)d_ws;
    _Float16* Wqh = (_Float16*)(ws + 256);
    _Float16* Wkh = Wqh + (size_t)DMODEL * DMODEL;
    _Float16* Wvh = Wkh + (size_t)DMODEL * DMODEL;
    _Float16* Woh = Wvh + (size_t)DMODEL * DMODEL;
    _Float16* q_ws  = Woh + (size_t)DMODEL * DMODEL;
    _Float16* k_ws  = q_ws + (size_t)MTOK * DMODEL;
    _Float16* vt_ws = k_ws + (size_t)MTOK * DMODEL;
    _Float16* a_ws  = vt_ws + (size_t)MTOK * DMODEL;
    unsigned long long* mb_ws =
        (unsigned long long*)(a_ws + (size_t)MTOK * DMODEL);  // 1 MB

    prep_kernel<<<dim3(512, 5), 256, 0, stream>>>(
        Wq, Wk, Wv, Wo, Wqh, Wkh, Wvh, Woh,
        (const unsigned char*)mask, (const unsigned int*)mask, mb_ws);

    dim3 gqkv(MTOK / 128, DMODEL / 128, 3);
    qkv_gemm16_kernel<<<gqkv, 256, 0, stream>>>(query, key_, value,
                                                Wqh, Wkh, Wvh,
                                                bq, bk, bv, q_ws, k_ws, vt_ws);

    dim3 gattn(SEQ / 128, 2 * NH);
    attn_kernel<<<gattn, 512, 0, stream>>>(q_ws, k_ws, vt_ws, mb_ws, a_ws);

    dim3 gout(MTOK / 64, DMODEL / 128);
    out_gemm16_kernel<<<gout, 256, 0, stream>>>(a_ws, Woh, bo, (float*)d_out);
}

// Round 12
// 249.311 us; speedup vs baseline: 1.1120x; 1.0836x over previous
//
#include <hip/hip_runtime.h>
#include <stdint.h>

#define MTOK   4096   // B*S
#define DMODEL 1024
#define SEQ    2048
#define NH     16
#define HD     64
#define LDP    68     // epilogue merge row stride (floats): (4q+d)%32 balanced
#define QSCL   0.18033688f   // 0.125 * log2(e): softmax in exp2 domain
#define NWORDS (2 * SEQ * SEQ / 64)   // 64-entry mask bit-words

typedef _Float16 h8  __attribute__((ext_vector_type(8)));
typedef _Float16 h4  __attribute__((ext_vector_type(4)));
typedef _Float16 h2  __attribute__((ext_vector_type(2)));
typedef __fp16   fp16x2 __attribute__((ext_vector_type(2)));
typedef float    f16v __attribute__((ext_vector_type(16)));
typedef float    f4  __attribute__((ext_vector_type(4)));
typedef int      iv4 __attribute__((ext_vector_type(4)));

typedef __attribute__((address_space(1))) const unsigned int g_u32;
typedef __attribute__((address_space(3))) unsigned int       l_u32;

// global->LDS direct DMA, 16 B/lane; LDS dest = wave-uniform base + lane*16.
__device__ __forceinline__ void g2l16(const void* g, void* l) {
    __builtin_amdgcn_global_load_lds((g_u32*)(unsigned long long)g,
                                     (l_u32*)(unsigned int)(unsigned long long)l,
                                     16, 0, 0);
}

__device__ __forceinline__ h2 pkrtz(float a, float b) {
    fp16x2 r = __builtin_amdgcn_cvt_pkrtz(a, b);
    return __builtin_bit_cast(h2, r);
}

#if __has_builtin(__builtin_amdgcn_exp2f)
#define E2(x) __builtin_amdgcn_exp2f(x)
#else
#define E2(x) exp2f(x)
#endif

// acc += sum of the two fp16 halves of dword v (v_dot2_f32_f16 with ones)
__device__ __forceinline__ float dot2sum(int v, float acc) {
    h2 a = __builtin_bit_cast(h2, v);
#if __has_builtin(__builtin_amdgcn_fdot2)
    h2 one2 = {(_Float16)1.0f, (_Float16)1.0f};
    return __builtin_amdgcn_fdot2(a, one2, acc, false);
#else
    return acc + (float)a.x + (float)a.y;
#endif
}

// ------------- prep: fp32->fp16 convert (z=0..6) + mask bitmask (z=7) -------
// R12: 8-wide conversion (2x float4 load -> 1x h8 16B store). R9's 8B h4
// stores were half-rate; store count now halved.
__global__ __launch_bounds__(256) void prep_kernel(
    const float* __restrict__ s0, const float* __restrict__ s1,
    const float* __restrict__ s2, const float* __restrict__ s3,
    const float* __restrict__ s4, const float* __restrict__ s5,
    const float* __restrict__ s6,
    _Float16* __restrict__ d0, _Float16* __restrict__ d1,
    _Float16* __restrict__ d2, _Float16* __restrict__ d3,
    _Float16* __restrict__ d4, _Float16* __restrict__ d5,
    _Float16* __restrict__ d6,
    const unsigned char* __restrict__ mb, const unsigned int* __restrict__ mu,
    unsigned long long* __restrict__ mout) {
    const int z = blockIdx.y;
    const int gid = blockIdx.x * 256 + threadIdx.x;
    const int stride = gridDim.x * 256;
    if (z < 7) {
        const float* s = (z == 0) ? s0 : (z == 1) ? s1 : (z == 2) ? s2
                       : (z == 3) ? s3 : (z == 4) ? s4 : (z == 5) ? s5 : s6;
        _Float16* d = (z == 0) ? d0 : (z == 1) ? d1 : (z == 2) ? d2
                    : (z == 3) ? d3 : (z == 4) ? d4 : (z == 5) ? d5 : d6;
        const int n8 = (z < 3) ? (MTOK * DMODEL / 8) : (DMODEL * DMODEL / 8);
        for (int i = gid; i < n8; i += stride) {
            float4 a = ((const float4*)s)[2 * i];
            float4 b = ((const float4*)s)[2 * i + 1];
            h8 o = {(_Float16)a.x, (_Float16)a.y, (_Float16)a.z, (_Float16)a.w,
                    (_Float16)b.x, (_Float16)b.y, (_Float16)b.z, (_Float16)b.w};
            ((h8*)d)[i] = o;
        }
    } else {
        // local byteflag: scan first 8192 mask bytes (L2-cached, all blocks)
        __shared__ int wsum[4];
        int cnt = 0;
        const uchar4* mp4 = (const uchar4*)mb;
#pragma unroll
        for (int i = 0; i < 8; ++i) {
            uchar4 v = mp4[threadIdx.x * 8 + i];
            cnt += (v.x != 0) + (v.y != 0) + (v.z != 0) + (v.w != 0);
        }
#pragma unroll
        for (int off = 32; off > 0; off >>= 1) cnt += __shfl_down(cnt, off, 64);
        if ((threadIdx.x & 63) == 0) wsum[threadIdx.x >> 6] = cnt;
        __syncthreads();
        const int byteflag = (wsum[0] + wsum[1] + wsum[2] + wsum[3]) > 2500;

        for (int w = gid; w < NWORDS; w += stride) {
            unsigned long long bits = 0ull;
            if (byteflag) {
                const uint4* p = (const uint4*)(mb + (size_t)w * 64);
#pragma unroll
                for (int i = 0; i < 4; ++i) {
                    uint4 v = p[i];
                    unsigned dw[4] = {v.x, v.y, v.z, v.w};
#pragma unroll
                    for (int j = 0; j < 4; ++j) {
                        unsigned d = dw[j];
                        unsigned nib = (unsigned)((d & 0xFFu) != 0)
                                     | ((unsigned)((d & 0xFF00u) != 0) << 1)
                                     | ((unsigned)((d & 0xFF0000u) != 0) << 2)
                                     | ((unsigned)((d >> 24) != 0) << 3);
                        bits |= (unsigned long long)nib << (i * 16 + j * 4);
                    }
                }
            } else {
                const uint4* p = (const uint4*)(mu + (size_t)w * 64);
#pragma unroll
                for (int i = 0; i < 16; ++i) {
                    uint4 v = p[i];
                    unsigned nib = (unsigned)(v.x != 0u)
                                 | ((unsigned)(v.y != 0u) << 1)
                                 | ((unsigned)(v.z != 0u) << 2)
                                 | ((unsigned)(v.w != 0u) << 3);
                    bits |= (unsigned long long)nib << (i * 4);
                }
            }
            mout[w] = bits;
        }
    }
}

// ------------- fp16 MFMA GEMM: out = A @ W^T + bias, BK=64, swizzled -------
// MODE 0: fp32 out[m][n].  MODE 1: fp16 head layout, value*scale (Q).
// MODE 3: K pre-swizzled attn-tile layout [bh][s/64][d/8][s%64][d%8].
// MODE 4: V^T (operand swap) pre-swizzled [bh][k/64][(k%64)/8][d][k%8].
// R12: DOUBLE-BUFFERED staging (attn's proven issue-early/drain-late
// schedule). R9/R11's loop was barrier->issue->barrier(drain)->compute:
// DMA latency fully exposed 16x/block (measured: qkv latency-bound at
// MfmaUtil 13-19%, all pipes idle). Now: issue STAGE(t+1) into buf^1,
// compute buf, ONE barrier (drains prefetch). Asb/Bsb are 2x buffers.
// LDS passed in (R9 lesson: per-instantiation static __shared__ unions).
template <int MODE, int BM, int BN>
__device__ __forceinline__ void gemm16_body(_Float16* __restrict__ Asb,
                                            _Float16* __restrict__ Bsb,
                                            const _Float16* __restrict__ A,
                                            const _Float16* __restrict__ W,
                                            const float* __restrict__ bias,
                                            void* __restrict__ outv,
                                            float scale, int m0, int n0) {
    constexpr int NI = BM / 32, NJ = BN / 32;
    constexpr int WM = BM / 2,  WN = BN / 2;
    constexpr int RA = BM / 32;  // g2l16 rounds (16B x 256 lanes = 32 rows)
    constexpr int RB = BN / 32;
    const int tid = threadIdx.x;
    const int wv = tid >> 6, lane = tid & 63;
    const int l15 = lane & 15, g = lane >> 4;
    const int wy = wv >> 1, wx = wv & 1;

    f4 acc[NI][NJ];
#pragma unroll
    for (int i = 0; i < NI; ++i)
#pragma unroll
        for (int j = 0; j < NJ; ++j) acc[i][j] = (f4){0.f, 0.f, 0.f, 0.f};

    const char* Ab = (const char*)A;
    const char* Wb = (const char*)W;
    int srowA[RA], scolA[RA];
#pragma unroll
    for (int r = 0; r < RA; ++r) {
        const int o = (r * 256 + tid) * 16;
        srowA[r] = o >> 7;
        scolA[r] = (((o >> 4) & 7) ^ (srowA[r] & 7)) * 16;
    }
    int srowB[RB], scolB[RB];
#pragma unroll
    for (int r = 0; r < RB; ++r) {
        const int o = (r * 256 + tid) * 16;
        srowB[r] = o >> 7;
        scolB[r] = (((o >> 4) & 7) ^ (srowB[r] & 7)) * 16;
    }

#define GSTAGE(kt, buf) do {                                                \
    const int k0b_ = (kt) * 128;                                            \
    char* ad_ = (char*)(Asb + (buf) * (BM * 64));                           \
    char* bd_ = (char*)(Bsb + (buf) * (BN * 64));                           \
    _Pragma("unroll")                                                       \
    for (int r = 0; r < RA; ++r)                                            \
        g2l16(Ab + (size_t)(m0 + srowA[r]) * 2048 + k0b_ + scolA[r],        \
              ad_ + (r * 256 + tid) * 16);                                  \
    _Pragma("unroll")                                                       \
    for (int r = 0; r < RB; ++r)                                            \
        g2l16(Wb + (size_t)(n0 + srowB[r]) * 2048 + k0b_ + scolB[r],        \
              bd_ + (r * 256 + tid) * 16);                                  \
} while (0)

    GSTAGE(0, 0);
    __syncthreads();           // drain prologue DMA

    for (int kt = 0; kt < 16; ++kt) {
        const int cur = kt & 1;
        if (kt < 15) GSTAGE(kt + 1, cur ^ 1);   // prefetch: lands during compute
        const _Float16* As = Asb + cur * (BM * 64);
        const _Float16* Bs = Bsb + cur * (BN * 64);

#pragma unroll
        for (int ksub = 0; ksub < 2; ++ksub) {
            h8 af[NI], bf[NJ];
#pragma unroll
            for (int t = 0; t < NI; ++t) {
                const int row = wy * WM + t * 16 + l15;
                const int pos = (ksub * 4 + g) ^ (row & 7);
                af[t] = *(const h8*)(As + row * 64 + pos * 8);
            }
#pragma unroll
            for (int t = 0; t < NJ; ++t) {
                const int row = wx * WN + t * 16 + l15;
                const int pos = (ksub * 4 + g) ^ (row & 7);
                bf[t] = *(const h8*)(Bs + row * 64 + pos * 8);
            }
#pragma unroll
            for (int i = 0; i < NI; ++i)
#pragma unroll
                for (int j = 0; j < NJ; ++j) {
                    if (MODE == 4)  // swapped: D rows = n (W), cols = m (X)
                        acc[i][j] = __builtin_amdgcn_mfma_f32_16x16x32_f16(
                            bf[j], af[i], acc[i][j], 0, 0, 0);
                    else
                        acc[i][j] = __builtin_amdgcn_mfma_f32_16x16x32_f16(
                            af[i], bf[j], acc[i][j], 0, 0, 0);
                }
        }
        __syncthreads();       // reads of buf done + prefetch drained
    }
#undef GSTAGE

    // epilogue: C/D layout col=lane&15, row=g*4+reg
#pragma unroll
    for (int j = 0; j < NJ; ++j) {
#pragma unroll
        for (int i = 0; i < NI; ++i) {
            if (MODE == 4) {
                // m = k (token), r iterates n -> (h,d). V_sw tile image.
                const int m = m0 + wy * WM + i * 16 + l15;
                const int b = m >> 11, s = m & 2047;
                const int koff = (s >> 6) * 4096 + ((s >> 3) & 7) * 512 + (s & 7);
#pragma unroll
                for (int r = 0; r < 4; ++r) {
                    const int n = n0 + wx * WN + j * 16 + g * 4 + r;
                    const int h = n >> 6, d = n & 63;
                    ((_Float16*)outv)[(size_t)(b * NH + h) * 131072 + koff + d * 8] =
                        (_Float16)(acc[i][j][r] + bias[n]);
                }
            } else {
                const int n = n0 + wx * WN + j * 16 + l15;
                const float bb = bias[n];
                const int mbase = m0 + wy * WM + i * 16 + g * 4;
                if (MODE == 1) {
                    const int h = n >> 6, d = n & 63;
#pragma unroll
                    for (int r = 0; r < 4; ++r) {
                        const int m = mbase + r;
                        const int b = m >> 11, s = m & 2047;
                        ((_Float16*)outv)[(((size_t)(b * NH + h)) * SEQ + s) * HD + d] =
                            (_Float16)((acc[i][j][r] + bb) * scale);
                    }
                } else if (MODE == 3) {
                    // n -> (h,d) fixed; r iterates m -> s. K_sw tile image.
                    const int h = n >> 6, d = n & 63;
                    const int doff = (d >> 3) * 512 + (d & 7);
#pragma unroll
                    for (int r = 0; r < 4; ++r) {
                        const int m = mbase + r;
                        const int b = m >> 11, s = m & 2047;
                        ((_Float16*)outv)[(size_t)(b * NH + h) * 131072 +
                                          (s >> 6) * 4096 + doff + (s & 63) * 8] =
                            (_Float16)(acc[i][j][r] + bb);
                    }
                } else {
#pragma unroll
                    for (int r = 0; r < 4; ++r)
                        ((float*)outv)[(size_t)(mbase + r) * DMODEL + n] =
                            acc[i][j][r] + bb;
                }
            }
        }
    }
}

// qkv (R12): fp16 A from prep (AF32 reverted: measured +22us on qkv);
// plain grid mapping (R9's default measured FETCH 37MB < any swizzle).
// LDS 64KB dbuf -> 2 blocks/CU; DMA hidden under compute per K-step.
__global__ __launch_bounds__(256) void qkv_gemm16_kernel(
    const _Float16* __restrict__ xq, const _Float16* __restrict__ xk,
    const _Float16* __restrict__ xv,
    const _Float16* __restrict__ Wq, const _Float16* __restrict__ Wk,
    const _Float16* __restrict__ Wv,
    const float* __restrict__ bq, const float* __restrict__ bk,
    const float* __restrict__ bv,
    _Float16* __restrict__ q_out, _Float16* __restrict__ k_out,
    _Float16* __restrict__ vt_out) {
    __shared__ __align__(16) _Float16 Asb[2 * 128 * 64];   // 32 KB
    __shared__ __align__(16) _Float16 Bsb[2 * 128 * 64];   // 32 KB
    const int m0 = blockIdx.x * 128, n0 = blockIdx.y * 128;
    const int z = blockIdx.z;
    if (z == 0)
        gemm16_body<1, 128, 128>(Asb, Bsb, xq, Wq, bq, (void*)q_out,
                                 QSCL, m0, n0);
    else if (z == 1)
        gemm16_body<3, 128, 128>(Asb, Bsb, xk, Wk, bk, (void*)k_out,
                                 1.0f, m0, n0);
    else
        gemm16_body<4, 128, 128>(Asb, Bsb, xv, Wv, bv, (void*)vt_out,
                                 1.0f, m0, n0);
}

__global__ __launch_bounds__(256) void out_gemm16_kernel(
    const _Float16* __restrict__ X, const _Float16* __restrict__ W,
    const float* __restrict__ bias, float* __restrict__ out) {
    __shared__ __align__(16) _Float16 Asb[2 * 64 * 64];    // 16 KB
    __shared__ __align__(16) _Float16 Bsb[2 * 128 * 64];   // 32 KB
    const int m0 = blockIdx.x * 64, n0 = blockIdx.y * 128;
    gemm16_body<0, 64, 128>(Asb, Bsb, X, W, bias, (void*)out, 1.0f, m0, n0);
}

// ---- MFMA flash attention (unchanged): pre-swizzled K/V + XCD swz ----
__global__ __launch_bounds__(512, 4) void attn_kernel(
    const _Float16* __restrict__ Q, const _Float16* __restrict__ Ksw,
    const _Float16* __restrict__ Vsw,
    const unsigned long long* __restrict__ mbits,
    _Float16* __restrict__ out) {
    // halves: K tiles [grp][buf] @ grp*8192+buf*4096 | V @ 16384+idem | LUT @ 32768
    __shared__ __align__(16) _Float16 shm[32768 + 64];

    const int tid = threadIdx.x;
    const int wv = tid >> 6, lane = tid & 63;
    const int grp = wv >> 2, wvg = wv & 3;
    const int l31 = lane & 31, hi = lane >> 5;
    // XCD swizzle: each XCD gets 4 whole bh (64 blocks = 4 bh x 16 q-tiles).
    const int lin = blockIdx.x + 16 * blockIdx.y;       // 0..511
    const int swz = (lin & 7) * 64 + (lin >> 3);        // bijective
    const int bh = swz >> 4;
    const int q0 = (swz & 15) * 128;
    const int b = bh >> 4, h = bh & 15;
    const size_t bho = (size_t)bh * (SEQ * HD);
    const int qrow = q0 + wvg * 32 + l31;  // this lane's q

    // mask-nibble -> fp16 AND-mask LUT (bit set = disallowed = zero)
    if (tid < 16) {
        unsigned mlo = (tid & 1 ? 0u : 0xFFFFu) | (tid & 2 ? 0u : 0xFFFF0000u);
        unsigned mhi = (tid & 4 ? 0u : 0xFFFFu) | (tid & 8 ? 0u : 0xFFFF0000u);
        ((uint2*)&shm[32768])[tid] = (uint2){mlo, mhi};
    }

    // Q B-frags, register-resident (pre-scaled by 0.125*log2e)
    h8 qf[4];
    const _Float16* qp = Q + bho + (size_t)qrow * HD;
#pragma unroll
    for (int ks = 0; ks < 4; ++ks) qf[ks] = *(const h8*)(qp + ks * 16 + hi * 8);

    f16v Ot[2];
#pragma unroll
    for (int mt = 0; mt < 2; ++mt)
#pragma unroll
        for (int r = 0; r < 16; ++r) Ot[mt][r] = 0.f;
    float l_r = 0.f;

    // staging: identity DMA. Tile t (8KB) lives at Ksw + bho + t*4096 halves
    // in the exact LDS image; 2 rounds of 256 threads x 16B cover it.
    const int gtid = tid & 255;
    const _Float16* ksrc = Ksw + bho + grp * 4096 + gtid * 8;
    const _Float16* vsrc = Vsw + bho + grp * 4096 + gtid * 8;
    const unsigned long long* mrow =
        mbits + ((size_t)b * SEQ + qrow) * (SEQ / 64);

    _Float16* KTb = &shm[grp * 8192];
    _Float16* VTb = &shm[16384 + grp * 8192];

#define STAGE(buf) do {                                                     \
    char* kd = (char*)(KTb + (buf) * 4096);                                 \
    char* vd = (char*)(VTb + (buf) * 4096);                                 \
    g2l16(ksrc,        kd + gtid * 16);                                     \
    g2l16(ksrc + 2048, kd + 4096 + gtid * 16);                              \
    g2l16(vsrc,        vd + gtid * 16);                                     \
    g2l16(vsrc + 2048, vd + 4096 + gtid * 16);                              \
    ksrc += 8192; vsrc += 8192;                                             \
} while (0)

    uint2 mw = *(const uint2*)(mrow + grp);  // mask of this group's tile 0
    STAGE(0);
    __syncthreads();   // drains vmcnt; LUT also visible

    const uint2* lut = (const uint2*)&shm[32768];
    int rp[8][2];

    for (int it = 0; it < 16; ++it) {
        const int cur = it & 1;
        const int kt = 2 * it + grp;
        uint2 mwn;
        if (it < 15) {  // prefetch group's next tile into other buffer
            STAGE(cur ^ 1);
            mwn = *(const uint2*)(mrow + kt + 2);
        }
        const _Float16* Kc = KTb + cur * 4096;
        const _Float16* Vc = VTb + cur * 4096;

        // ---- S^T = K . Q^T : lane pair holds 64 scores of its q ----
        f16v sc0, sc1;
#pragma unroll
        for (int r = 0; r < 16; ++r) { sc0[r] = 0.f; sc1[r] = 0.f; }
        __builtin_amdgcn_s_setprio(1);
#pragma unroll
        for (int ks = 0; ks < 4; ++ks) {
            const int po = (2 * ks + hi) * 512;   // chunk column, halves
            h8 kf0 = *(const h8*)(Kc + po + l31 * 8);
            h8 kf1 = *(const h8*)(Kc + po + 256 + l31 * 8);
            sc0 = __builtin_amdgcn_mfma_f32_32x32x16_f16(kf0, qf[ks], sc0, 0, 0, 0);
            sc1 = __builtin_amdgcn_mfma_f32_32x32x16_f16(kf1, qf[ks], sc1, 0, 0, 0);
        }
        __builtin_amdgcn_s_setprio(0);

        // ---- softmax: exp2 unconditionally, AND with LUT mask, pack ----
#pragma unroll
        for (int mt = 0; mt < 2; ++mt) {
            const unsigned w = mt ? mw.y : mw.x;
            const unsigned wl = w >> (hi * 4);
            const f16v& s = mt ? sc1 : sc0;
#pragma unroll
            for (int g4 = 0; g4 < 4; ++g4) {
                const uint2 m2 = lut[(wl >> (g4 * 8)) & 15u];
                float p0 = E2(s[g4 * 4 + 0]);
                float p1 = E2(s[g4 * 4 + 1]);
                float p2 = E2(s[g4 * 4 + 2]);
                float p3 = E2(s[g4 * 4 + 3]);
                rp[mt * 4 + g4][0] =
                    __builtin_bit_cast(int, pkrtz(p0, p1)) & (int)m2.x;
                rp[mt * 4 + g4][1] =
                    __builtin_bit_cast(int, pkrtz(p2, p3)) & (int)m2.y;
            }
        }

        // ---- permlane exchange -> PV B-frags; l via dot2; O^T += V^T.P ----
        float l0 = 0.f, l1 = 0.f;
#pragma unroll
        for (int ks = 0; ks < 4; ++ks) {
            int a0 = rp[2 * ks][0], a1 = rp[2 * ks][1];
            int b0 = rp[2 * ks + 1][0], b1 = rp[2 * ks + 1][1];
            asm volatile("v_permlane32_swap_b32 %0, %1" : "+v"(a0), "+v"(b0));
            asm volatile("v_permlane32_swap_b32 %0, %1" : "+v"(a1), "+v"(b1));
            l0 = dot2sum(a0, l0); l1 = dot2sum(a1, l1);
            l0 = dot2sum(b0, l0); l1 = dot2sum(b1, l1);
            iv4 pi = {a0, a1, b0, b1};
            h8 pf = __builtin_bit_cast(h8, pi);
            const int po = (2 * ks + hi) * 512;
            h8 vf0 = *(const h8*)(Vc + po + l31 * 8);
            h8 vf1 = *(const h8*)(Vc + po + 256 + l31 * 8);
            __builtin_amdgcn_s_setprio(1);
            Ot[0] = __builtin_amdgcn_mfma_f32_32x32x16_f16(vf0, pf, Ot[0], 0, 0, 0);
            Ot[1] = __builtin_amdgcn_mfma_f32_32x32x16_f16(vf1, pf, Ot[1], 0, 0, 0);
            __builtin_amdgcn_s_setprio(0);
        }
        l_r += l0 + l1;

        if (it < 15) mw = mwn;
        __syncthreads();  // one barrier/iter; drains prefetch g2l16s
    }
#undef STAGE

    // ---- epilogue: merge groups via LDS (stride LDP=68), store fp16 ----
    l_r += __shfl_xor(l_r, 32);                 // merge hi halves within group
    float* mrg = (float*)&shm[0];               // 128 x LDP floats
    float* lm  = mrg + 128 * LDP;               // 128 floats
    const int ql = wvg * 32 + l31;
    if (grp == 1) {
#pragma unroll
        for (int mt = 0; mt < 2; ++mt)
#pragma unroll
            for (int t = 0; t < 4; ++t) {
                f4 v = {Ot[mt][t * 4 + 0], Ot[mt][t * 4 + 1],
                        Ot[mt][t * 4 + 2], Ot[mt][t * 4 + 3]};
                *(f4*)&mrg[ql * LDP + mt * 32 + t * 8 + hi * 4] = v;
            }
        if (hi == 0) lm[ql] = l_r;
    }
    __syncthreads();
    if (grp == 0) {
        l_r += lm[ql];
        const float inv = 1.0f / l_r;
        _Float16* op = out + ((size_t)b * SEQ + qrow) * DMODEL + h * HD;
#pragma unroll
        for (int mt = 0; mt < 2; ++mt)
#pragma unroll
            for (int t = 0; t < 4; ++t) {
                const int d = mt * 32 + t * 8 + hi * 4;
                f4 v = *(const f4*)&mrg[ql * LDP + d];
                h4 ov = {(_Float16)((Ot[mt][t * 4 + 0] + v.x) * inv),
                         (_Float16)((Ot[mt][t * 4 + 1] + v.y) * inv),
                         (_Float16)((Ot[mt][t * 4 + 2] + v.z) * inv),
                         (_Float16)((Ot[mt][t * 4 + 3] + v.w) * inv)};
                *(h4*)(op + d) = ov;
            }
    }
}

extern "C" void kernel_launch(void* const* d_in, const int* in_sizes, int n_in,
                              void* d_out, int out_size, void* d_ws, size_t ws_size,
                              hipStream_t stream) {
    const float* query = (const float*)d_in[0];
    const float* key_  = (const float*)d_in[1];
    const float* value = (const float*)d_in[2];
    const void*  mask  = d_in[3];
    const float* Wq = (const float*)d_in[4];
    const float* Wk = (const float*)d_in[5];
    const float* Wv = (const float*)d_in[6];
    const float* Wo = (const float*)d_in[7];
    const float* bq = (const float*)d_in[8];
    const float* bk = (const float*)d_in[9];
    const float* bv = (const float*)d_in[10];
    const float* bo = (const float*)d_in[11];

    char* ws = (char*)d_ws;
    _Float16* xq  = (_Float16*)(ws + 256);
    _Float16* xk  = xq + (size_t)MTOK * DMODEL;
    _Float16* xv  = xk + (size_t)MTOK * DMODEL;
    _Float16* Wqh = xv + (size_t)MTOK * DMODEL;
    _Float16* Wkh = Wqh + (size_t)DMODEL * DMODEL;
    _Float16* Wvh = Wkh + (size_t)DMODEL * DMODEL;
    _Float16* Woh = Wvh + (size_t)DMODEL * DMODEL;
    _Float16* q_ws  = Woh + (size_t)DMODEL * DMODEL;
    _Float16* k_ws  = q_ws + (size_t)MTOK * DMODEL;
    _Float16* vt_ws = k_ws + (size_t)MTOK * DMODEL;
    _Float16* a_ws  = vt_ws + (size_t)MTOK * DMODEL;
    unsigned long long* mb_ws =
        (unsigned long long*)(a_ws + (size_t)MTOK * DMODEL);  // 1 MB

    prep_kernel<<<dim3(1024, 8), 256, 0, stream>>>(
        query, key_, value, Wq, Wk, Wv, Wo, xq, xk, xv, Wqh, Wkh, Wvh, Woh,
        (const unsigned char*)mask, (const unsigned int*)mask, mb_ws);

    dim3 gqkv(MTOK / 128, DMODEL / 128, 3);
    qkv_gemm16_kernel<<<gqkv, 256, 0, stream>>>(xq, xk, xv, Wqh, Wkh, Wvh,
                                                bq, bk, bv, q_ws, k_ws, vt_ws);

    dim3 gattn(SEQ / 128, 2 * NH);
    attn_kernel<<<gattn, 512, 0, stream>>>(q_ws, k_ws, vt_ws, mb_ws, a_ws);

    dim3 gout(MTOK / 64, DMODEL / 128);
    out_gemm16_kernel<<<gout, 256, 0, stream>>>(a_ws, Woh, bo, (float*)d_out);
}